// Round 6
// baseline (421.873 us; speedup 1.0000x reference)
//
#include <hip/hip_runtime.h>
#include <math.h>

#define NNODES 50000
#define NEDGES 800000
#define NLAYERS 3
#define NHEADS 2
#define NCH 64
#define FDIM 128   // == NHEADS*NCH
#define NCLS 10
#define NGRAPH 64
#define NEG_SLOPE 0.2f
#define NBLK ((NNODES + 255) / 256)   // 196
#define GEMMB ((NNODES + 63) / 64)    // 782
#define AGGB ((NNODES + 3) / 4)       // 12500 blocks per head
#define POOLB ((NNODES + 63) / 64)    // 782
#define NB 391                        // buckets = ceil(50000/128)
#define RADB 391                      // radix blocks = ceil(800000/2048)
#define SCN (NB * RADB)               // 152881
#define NS1 ((SCN + 511) / 512)       // 299

#define WAVE_SYNC()                      \
  do {                                   \
    __builtin_amdgcn_wave_barrier();     \
    __asm__ volatile("" ::: "memory");   \
  } while (0)

typedef __attribute__((ext_vector_type(8))) short bf16x8;
typedef __attribute__((ext_vector_type(4))) float f32x4;

__device__ __forceinline__ unsigned short f2bf(float f) {
  unsigned int u = __builtin_bit_cast(unsigned int, f);
  unsigned int r = u + 0x7FFFu + ((u >> 16) & 1u);  // RNE
  return (unsigned short)(r >> 16);
}
__device__ __forceinline__ float bflo(unsigned v) {
  return __builtin_bit_cast(float, v << 16);
}
__device__ __forceinline__ float bfhi(unsigned v) {
  return __builtin_bit_cast(float, v & 0xFFFF0000u);
}

// ---------------- W prep: transpose + bf16 (3 blocks, one per layer) -------
__global__ __launch_bounds__(256) void k_wprep(const float* __restrict__ W,
                                               unsigned* __restrict__ Wt) {
  __shared__ float Lt[128][132];
  int l = blockIdx.x;
  const float* Wl = W + (size_t)l * FDIM * FDIM;
  unsigned* Wtl = Wt + (size_t)l * FDIM * FDIM / 2;
  int t = threadIdx.x;
#pragma unroll
  for (int i = 0; i < 16; ++i) {
    int k = (t >> 5) + 8 * i;
    int n4 = (t & 31) * 4;
    float4 v = *(const float4*)(Wl + (size_t)k * 128 + n4);
    Lt[k][n4 + 0] = v.x;
    Lt[k][n4 + 1] = v.y;
    Lt[k][n4 + 2] = v.z;
    Lt[k][n4 + 3] = v.w;
  }
  __syncthreads();
  int n = t >> 1;
  int kh = (t & 1) * 64;
  for (int kk = 0; kk < 64; kk += 2) {
    unsigned pk = (unsigned)f2bf(Lt[kh + kk][n]) |
                  ((unsigned)f2bf(Lt[kh + kk + 1][n]) << 16);
    Wtl[n * 64 + (kh >> 1) + (kk >> 1)] = pk;
  }
}

// ---------------- MFMA GEMM body (no LDS) ----------------
// H[row,:] = X[row,:] @ W. Writes head-split packed-bf16 Hb0/Hb1 and alphas.
__device__ __forceinline__ void gemm_body(
    int blk, const float* __restrict__ X, const unsigned* __restrict__ Wt,
    const float* __restrict__ a_sL, const float* __restrict__ a_dL,
    unsigned* __restrict__ Hb0, unsigned* __restrict__ Hb1,
    float* __restrict__ as0, float* __restrict__ ad0, float* __restrict__ as1,
    float* __restrict__ ad1) {
  int t = threadIdx.x;
  int lane = t & 63;
  int w = t >> 6;
  int row0 = blk * 64;
  int n16 = lane & 15;
  int quad = lane >> 4;
  int m0 = w * 16;

  int gr = row0 + m0 + n16;
  const float* xp = X + (size_t)min(gr, NNODES - 1) * 128;

  f32x4 acc[8];
#pragma unroll
  for (int nt = 0; nt < 8; ++nt) {
    f32x4 z = {0.f, 0.f, 0.f, 0.f};
    acc[nt] = z;
  }
#pragma unroll
  for (int kk = 0; kk < 4; ++kk) {
    float4 va = *(const float4*)(xp + kk * 32 + quad * 8);
    float4 vb = *(const float4*)(xp + kk * 32 + quad * 8 + 4);
    bf16x8 af;
    af[0] = (short)f2bf(va.x); af[1] = (short)f2bf(va.y);
    af[2] = (short)f2bf(va.z); af[3] = (short)f2bf(va.w);
    af[4] = (short)f2bf(vb.x); af[5] = (short)f2bf(vb.y);
    af[6] = (short)f2bf(vb.z); af[7] = (short)f2bf(vb.w);
#pragma unroll
    for (int nt = 0; nt < 8; ++nt) {
      bf16x8 bf = *(const bf16x8*)(Wt + (size_t)(nt * 16 + n16) * 64 +
                                   kk * 16 + quad * 4);
      acc[nt] =
          __builtin_amdgcn_mfma_f32_16x16x32_bf16(af, bf, acc[nt], 0, 0, 0);
    }
  }

  // epilogue: alpha dots + head-split packed-bf16 H write
  float asv[8], adv[8];
#pragma unroll
  for (int nt = 0; nt < 8; ++nt) {
    asv[nt] = a_sL[nt * 16 + n16];
    adv[nt] = a_dL[nt * 16 + n16];
  }
#pragma unroll
  for (int r = 0; r < 4; ++r) {
    int row = row0 + m0 + quad * 4 + r;
    bool ok = (row < NNODES);
    float ps0 = 0.f, pd0 = 0.f, ps1 = 0.f, pd1 = 0.f;
#pragma unroll
    for (int nt = 0; nt < 4; ++nt) {
      ps0 += acc[nt][r] * asv[nt];
      pd0 += acc[nt][r] * adv[nt];
      ps1 += acc[nt + 4][r] * asv[nt + 4];
      pd1 += acc[nt + 4][r] * adv[nt + 4];
    }
#pragma unroll
    for (int off = 1; off < 16; off <<= 1) {
      ps0 += __shfl_xor(ps0, off, 64);
      pd0 += __shfl_xor(pd0, off, 64);
      ps1 += __shfl_xor(ps1, off, 64);
      pd1 += __shfl_xor(pd1, off, 64);
    }
    if (ok && n16 == 0) {
      as0[row] = ps0;
      ad0[row] = pd0;
      as1[row] = ps1;
      ad1[row] = pd1;
    }
    if (ok) {
      // head0: dword d = nt*16+n16 holds channels (d, d+32) of head0
#pragma unroll
      for (int nt = 0; nt < 2; ++nt) {
        unsigned p0 = (unsigned)f2bf(acc[nt][r]) |
                      ((unsigned)f2bf(acc[nt + 2][r]) << 16);
        Hb0[(size_t)row * 32 + nt * 16 + n16] = p0;
        unsigned p1 = (unsigned)f2bf(acc[nt + 4][r]) |
                      ((unsigned)f2bf(acc[nt + 6][r]) << 16);
        Hb1[(size_t)row * 32 + nt * 16 + n16] = p1;
      }
    }
  }
}

__global__ __launch_bounds__(256) void k_gemm(
    const float* __restrict__ X, const unsigned* __restrict__ Wt,
    const float* __restrict__ a_sL, const float* __restrict__ a_dL,
    unsigned* __restrict__ Hb0, unsigned* __restrict__ Hb1,
    float* __restrict__ as0, float* __restrict__ ad0, float* __restrict__ as1,
    float* __restrict__ ad1) {
  gemm_body(blockIdx.x, X, Wt, a_sL, a_dL, Hb0, Hb1, as0, ad0, as1, ad1);
}

// fused: layer-0 GEMM | radix pass A (bucket histogram) | per-graph count.
__global__ __launch_bounds__(256) void k_front(
    const float* __restrict__ X, const unsigned* __restrict__ Wt,
    const float* __restrict__ a_sL, const float* __restrict__ a_dL,
    unsigned* __restrict__ Hb0, unsigned* __restrict__ Hb1,
    float* __restrict__ as0, float* __restrict__ ad0, float* __restrict__ as1,
    float* __restrict__ ad1, const int* __restrict__ ei, int* __restrict__ bh,
    const int* __restrict__ batch, float* __restrict__ gcnt) {
  int b = blockIdx.x;
  if (b < GEMMB) {
    gemm_body(b, X, Wt, a_sL, a_dL, Hb0, Hb1, as0, ad0, as1, ad1);
  } else if (b < GEMMB + RADB) {
    __shared__ int hist[NB];
    int blk = b - GEMMB;
    int t = threadIdx.x;
    for (int i = t; i < NB; i += 256) hist[i] = 0;
    __syncthreads();
    int e0 = blk * 2048;
#pragma unroll
    for (int i = 0; i < 8; ++i) {
      int e = e0 + i * 256 + t;
      if (e < NEDGES) atomicAdd(&hist[ei[NEDGES + e] >> 7], 1);
    }
    __syncthreads();
    for (int i = t; i < NB; i += 256) bh[i * RADB + blk] = hist[i];
  } else {
    __shared__ float loc[NGRAPH];
    int t = threadIdx.x;
    if (t < NGRAPH) loc[t] = 0.f;
    __syncthreads();
    int n = (b - GEMMB - RADB) * 256 + t;
    if (n < NNODES) atomicAdd(&loc[batch[n]], 1.f);
    __syncthreads();
    if (t < NGRAPH && loc[t] > 0.f) atomicAdd(&gcnt[t], loc[t]);
  }
}

// ---------------- scan of bh; last block also scans the partials ----------
__global__ __launch_bounds__(256) void k_s1(int* __restrict__ sc,
                                            int* __restrict__ bpart,
                                            int* __restrict__ dcnt) {
  __shared__ int ps[256];
  int t = threadIdx.x;
  int f0 = blockIdx.x * 512 + 2 * t;
  int x0 = (f0 < SCN) ? sc[f0] : 0;
  int x1 = (f0 + 1 < SCN) ? sc[f0 + 1] : 0;
  int pair = x0 + x1;
  ps[t] = pair;
  __syncthreads();
  for (int off = 1; off < 256; off <<= 1) {
    int v = (t >= off) ? ps[t - off] : 0;
    __syncthreads();
    ps[t] += v;
    __syncthreads();
  }
  int ex = ps[t] - pair;
  if (f0 < SCN) sc[f0] = ex;
  if (f0 + 1 < SCN) sc[f0 + 1] = ex + x0;
  if (t == 255) bpart[blockIdx.x] = ps[255];
  __threadfence();
  __syncthreads();
  __shared__ int lastf;
  if (t == 0) lastf = (atomicAdd(dcnt, 1) == NS1 - 1) ? 1 : 0;
  __syncthreads();
  if (!lastf) return;
  __threadfence();
  // scan the NS1 partials (this block only)
  int y0 = (2 * t < NS1) ? bpart[2 * t] : 0;
  int y1 = (2 * t + 1 < NS1) ? bpart[2 * t + 1] : 0;
  int pr = y0 + y1;
  __syncthreads();
  ps[t] = pr;
  __syncthreads();
  for (int off = 1; off < 256; off <<= 1) {
    int v = (t >= off) ? ps[t - off] : 0;
    __syncthreads();
    ps[t] += v;
    __syncthreads();
  }
  int ex2 = ps[t] - pr;
  if (2 * t < NS1) bpart[2 * t] = ex2;
  if (2 * t + 1 < NS1) bpart[2 * t + 1] = ex2 + y0;
}

__global__ __launch_bounds__(256) void k_s3(int* __restrict__ sc,
                                            const int* __restrict__ bpart) {
  int t = threadIdx.x;
  int f0 = blockIdx.x * 512 + 2 * t;
  int add = bpart[blockIdx.x];
  if (f0 < SCN) sc[f0] += add;
  if (f0 + 1 < SCN) sc[f0 + 1] += add;
}

// ---------------- radix pass B: scatter edges into bucket regions ---------
__global__ __launch_bounds__(256) void k_passB(const int* __restrict__ ei,
                                               const int* __restrict__ sc,
                                               unsigned* __restrict__ ebuf) {
  __shared__ int curs[NB];
  int blk = blockIdx.x, t = threadIdx.x;
  for (int i = t; i < NB; i += 256) curs[i] = sc[i * RADB + blk];
  __syncthreads();
  int e0 = blk * 2048;
#pragma unroll
  for (int i = 0; i < 8; ++i) {
    int e = e0 + i * 256 + t;
    if (e < NEDGES) {
      int s = ei[e];
      int d = ei[NEDGES + e];
      int pos = atomicAdd(&curs[d >> 7], 1);
      ebuf[pos] = ((unsigned)s << 7) | (unsigned)(d & 127);
    }
  }
}

// ---------------- radix pass C: per-bucket CSR finalize ----------------
__global__ __launch_bounds__(256) void k_passC(const unsigned* __restrict__ ebuf,
                                               const int* __restrict__ sc,
                                               int* __restrict__ row_ptr,
                                               int* __restrict__ csr) {
  __shared__ int deg[128];
  __shared__ int scn[128];
  int b = blockIdx.x, t = threadIdx.x;
  int node0 = b * 128;
  int nn = min(128, NNODES - node0);
  int estart = sc[b * RADB];
  int eend = (b + 1 < NB) ? sc[(b + 1) * RADB] : NEDGES;
  if (t < 128) deg[t] = 0;
  __syncthreads();
  for (int e = estart + t; e < eend; e += 256)
    atomicAdd(&deg[ebuf[e] & 127], 1);
  __syncthreads();
  if (t < 128) scn[t] = (t < nn) ? deg[t] + 1 : 0;
  __syncthreads();
  for (int off = 1; off < 128; off <<= 1) {
    int v = (t < 128 && t >= off) ? scn[t - off] : 0;
    __syncthreads();
    if (t < 128) scn[t] += v;
    __syncthreads();
  }
  int base = estart + node0;
  if (t < nn) {
    int st = base + (t ? scn[t - 1] : 0);
    row_ptr[node0 + t] = st;
    csr[st] = node0 + t;  // self-loop at rank 0
    deg[t] = st + 1;      // reuse as cursor
  }
  if (b == 0 && t == 0) row_ptr[NNODES] = NEDGES + NNODES;
  __syncthreads();
  for (int e = estart + t; e < eend; e += 256) {
    unsigned v = ebuf[e];
    int pos = atomicAdd(&deg[v & 127], 1);
    csr[pos] = (int)(v >> 7);
  }
}

// One wave per (node, processing 2 edges/iter). Head chosen by block range:
// blocks [0,AGGB) head0, [AGGB,2*AGGB) head1 — temporal split keeps the
// 6.4 MB per-head table hot in per-XCD L2.
__global__ __launch_bounds__(256) void k_aggregate(
    const unsigned* __restrict__ Hb0, const unsigned* __restrict__ Hb1,
    const float* __restrict__ as0, const float* __restrict__ ad0,
    const float* __restrict__ as1, const float* __restrict__ ad1,
    const int* __restrict__ row_ptr, const int* __restrict__ csr,
    const float* __restrict__ bias, float* __restrict__ Xout) {
  __shared__ float wb[4][64];
  __shared__ int sb[4][64];
  int hb = (blockIdx.x >= AGGB) ? 1 : 0;
  int blk = blockIdx.x - hb * AGGB;
  const unsigned* Hh = hb ? Hb1 : Hb0;
  const float* ash = hb ? as1 : as0;
  const float* adh = hb ? ad1 : ad0;
  int wv = threadIdx.x >> 6;
  int lane = threadIdx.x & 63;
  int node = blk * 4 + wv;
  if (node >= NNODES) return;
  int rs = row_ptr[node], re = row_ptr[node + 1];
  float adv = adh[node];
  int eh = lane >> 5;
  int l32 = lane & 31;
  const unsigned* Hl = Hh + l32;

  float z = 0.f, accL = 0.f, accH = 0.f;
  for (int base = rs; base < re; base += 64) {
    int j = base + lane;
    float p = 0.f;
    int s = 0;
    if (j < re) {
      s = csr[j];
      float e = ash[s] + adv;
      e = (e > 0.f) ? e : NEG_SLOPE * e;
      p = __expf(e);
    }
    z += p;
    wb[wv][lane] = p;
    sb[wv][lane] = s;
    WAVE_SYNC();
    int cl = min(64, re - base);
    int jj = 0;
    for (; jj + 16 <= cl; jj += 16) {  // 8 edge-pairs in flight
#pragma unroll
      for (int u = 0; u < 8; ++u) {
        int idx = jj + 2 * u + eh;
        int s_ = sb[wv][idx];
        float w_ = wb[wv][idx];
        unsigned v = Hl[(size_t)s_ * 32];
        accL += w_ * bflo(v);
        accH += w_ * bfhi(v);
      }
    }
    for (; jj < cl; jj += 2) {
      int idx = jj + eh;
      int s_ = sb[wv][(idx < cl) ? idx : 0];
      float w_ = (idx < cl) ? wb[wv][idx] : 0.f;
      unsigned v = Hl[(size_t)s_ * 32];
      accL += w_ * bflo(v);
      accH += w_ * bfhi(v);
    }
    WAVE_SYNC();
  }
#pragma unroll
  for (int off = 32; off > 0; off >>= 1) z += __shfl_xor(z, off, 64);
  accL += __shfl_xor(accL, 32, 64);
  accH += __shfl_xor(accH, 32, 64);
  // lane < 32 holds channel l32 (accL), lane >= 32 channel l32+32 (accH)
  float o = (eh == 0) ? accL : accH;
  o = o / z + bias[hb * 64 + lane];
  o = (o > 0.f) ? o : expm1f(o);  // ELU
  Xout[(size_t)node * 128 + hb * 64 + lane] = o;
}

// ---------------- pooling + fused classifier (last block) ----------------

__global__ __launch_bounds__(128) void k_pool(
    const float* __restrict__ Xf, const int* __restrict__ batch,
    float* __restrict__ gsum, const float* __restrict__ gcnt,
    const float* __restrict__ lw, const float* __restrict__ lb,
    float* __restrict__ out, int* __restrict__ pdone) {
  int c = threadIdx.x;
  int n0 = blockIdx.x * 64;
  int n1 = min(n0 + 64, NNODES);
  int cur = batch[n0];
  float acc = 0.f;
  for (int n = n0; n < n1; ++n) {
    int g = batch[n];
    if (g != cur) {
      atomicAdd(&gsum[cur * FDIM + c], acc);
      acc = 0.f;
      cur = g;
    }
    acc += Xf[(size_t)n * 128 + c];
  }
  atomicAdd(&gsum[cur * FDIM + c], acc);
  __threadfence();
  __syncthreads();
  __shared__ int lastf;
  if (c == 0) lastf = (atomicAdd(pdone, 1) == POOLB - 1) ? 1 : 0;
  __syncthreads();
  if (!lastf) return;
  __threadfence();
  if (c < NGRAPH) {
    int g = c;
    float inv = 1.f / fmaxf(gcnt[g], 1.f);
    float lg[NCLS];
#pragma unroll
    for (int k = 0; k < NCLS; ++k) lg[k] = lb[k];
    for (int ch = 0; ch < FDIM; ++ch) {
      float pv = gsum[g * FDIM + ch] * inv;
#pragma unroll
      for (int k = 0; k < NCLS; ++k) lg[k] += pv * lw[ch * NCLS + k];
    }
    float mx = lg[0];
#pragma unroll
    for (int k = 1; k < NCLS; ++k) mx = fmaxf(mx, lg[k]);
    float s = 0.f;
#pragma unroll
    for (int k = 0; k < NCLS; ++k) {
      lg[k] = expf(lg[k] - mx);
      s += lg[k];
    }
    float invs = 1.f / s;
#pragma unroll
    for (int k = 0; k < NCLS; ++k) out[g * NCLS + k] = lg[k] * invs;
  }
}

// ---------------- launch ----------------

extern "C" void kernel_launch(void* const* d_in, const int* in_sizes, int n_in,
                              void* d_out, int out_size, void* d_ws,
                              size_t ws_size, hipStream_t stream) {
  const float* x = (const float*)d_in[0];
  const int* ei = (const int*)d_in[1];
  const int* batch = (const int*)d_in[2];
  const float* W = (const float*)d_in[3];
  const float* a_s = (const float*)d_in[4];
  const float* a_d = (const float*)d_in[5];
  const float* bias = (const float*)d_in[6];
  const float* lw = (const float*)d_in[7];
  const float* lb = (const float*)d_in[8];
  float* out = (float*)d_out;

  unsigned* Hb0 = (unsigned*)d_ws;                  // N*32 head0 bf16 pairs
  unsigned* Hb1 = Hb0 + (size_t)NNODES * 32;        // N*32 head1
  float* xb = (float*)(Hb1 + (size_t)NNODES * 32);  // N*128
  float* as0 = xb + (size_t)NNODES * 128;           // N
  float* ad0 = as0 + NNODES;                        // N
  float* as1 = ad0 + NNODES;                        // N
  float* ad1 = as1 + NNODES;                        // N
  float* gsum = ad1 + NNODES;                       // 64*128 } one memset
  float* gcnt = gsum + NGRAPH * FDIM;               // 64     }
  int* dcnt = (int*)(gcnt + NGRAPH);                // 1      }
  int* pdone = dcnt + 1;                            // 1      }
  int* row_ptr = pdone + 1;                         // N+1
  int* csr = row_ptr + (NNODES + 1);                // E+N
  int* sc = csr + (NEDGES + NNODES);                // NB*RADB
  int* bpart = sc + SCN;                            // NS1
  unsigned* ebuf = (unsigned*)(bpart + NS1);        // E (+pad)
  unsigned* Wt = ebuf + (NEDGES + 1024);            // 3*8192 (bf16 W^T)

  hipMemsetAsync(gsum, 0, (NGRAPH * FDIM + NGRAPH + 2) * 4, stream);
  k_wprep<<<NLAYERS, 256, 0, stream>>>(W, Wt);
  // layer-0 GEMM overlapped with radix pass A + graph-size count
  k_front<<<GEMMB + RADB + NBLK, 256, 0, stream>>>(
      x, Wt, a_s, a_d, Hb0, Hb1, as0, ad0, as1, ad1, ei, sc, batch, gcnt);
  k_s1<<<NS1, 256, 0, stream>>>(sc, bpart, dcnt);
  k_s3<<<NS1, 256, 0, stream>>>(sc, bpart);
  k_passB<<<RADB, 256, 0, stream>>>(ei, sc, ebuf);
  k_passC<<<NB, 256, 0, stream>>>(ebuf, sc, row_ptr, csr);

  for (int l = 0; l < NLAYERS; ++l) {
    if (l > 0) {
      k_gemm<<<GEMMB, 256, 0, stream>>>(xb, Wt + (size_t)l * FDIM * FDIM / 2,
                                        a_s + l * FDIM, a_d + l * FDIM, Hb0,
                                        Hb1, as0, ad0, as1, ad1);
    }
    k_aggregate<<<2 * AGGB, 256, 0, stream>>>(Hb0, Hb1, as0, ad0, as1, ad1,
                                              row_ptr, csr, bias + l * FDIM,
                                              xb);
  }
  k_pool<<<POOLB, 128, 0, stream>>>(xb, batch, gsum, gcnt, lw, lb, out, pdone);
}

// Round 7
// 324.165 us; speedup vs baseline: 1.3014x; 1.3014x over previous
//
#include <hip/hip_runtime.h>
#include <math.h>

#define NNODES 50000
#define NEDGES 800000
#define NLAYERS 3
#define NHEADS 2
#define NCH 64
#define FDIM 128   // == NHEADS*NCH
#define NCLS 10
#define NGRAPH 64
#define NEG_SLOPE 0.2f
#define GEMMB ((NNODES + 63) / 64)    // 782
#define NB 391                        // buckets = ceil(50000/128)
#define RADB 391                      // radix blocks = ceil(800000/2048)
#define SCN (NB * RADB)               // 152881
#define NS1 ((SCN + 511) / 512)       // 299
#define PCH 8                         // pool chunks per graph

#define WAVE_SYNC()                      \
  do {                                   \
    __builtin_amdgcn_wave_barrier();     \
    __asm__ volatile("" ::: "memory");   \
  } while (0)

typedef __attribute__((ext_vector_type(8))) short bf16x8;
typedef __attribute__((ext_vector_type(4))) float f32x4;

__device__ __forceinline__ unsigned short f2bf(float f) {
  unsigned int u = __builtin_bit_cast(unsigned int, f);
  unsigned int r = u + 0x7FFFu + ((u >> 16) & 1u);  // RNE
  return (unsigned short)(r >> 16);
}
__device__ __forceinline__ float bflo(unsigned v) {
  return __builtin_bit_cast(float, v << 16);
}
__device__ __forceinline__ float bfhi(unsigned v) {
  return __builtin_bit_cast(float, v & 0xFFFF0000u);
}

// ---------------- W prep: transpose + bf16 (3 blocks, one per layer) -------
__global__ __launch_bounds__(256) void k_wprep(const float* __restrict__ W,
                                               unsigned* __restrict__ Wt) {
  __shared__ float Lt[128][132];
  int l = blockIdx.x;
  const float* Wl = W + (size_t)l * FDIM * FDIM;
  unsigned* Wtl = Wt + (size_t)l * FDIM * FDIM / 2;
  int t = threadIdx.x;
#pragma unroll
  for (int i = 0; i < 16; ++i) {
    int k = (t >> 5) + 8 * i;
    int n4 = (t & 31) * 4;
    float4 v = *(const float4*)(Wl + (size_t)k * 128 + n4);
    Lt[k][n4 + 0] = v.x;
    Lt[k][n4 + 1] = v.y;
    Lt[k][n4 + 2] = v.z;
    Lt[k][n4 + 3] = v.w;
  }
  __syncthreads();
  int n = t >> 1;
  int kh = (t & 1) * 64;
  for (int kk = 0; kk < 64; kk += 2) {
    unsigned pk = (unsigned)f2bf(Lt[kh + kk][n]) |
                  ((unsigned)f2bf(Lt[kh + kk + 1][n]) << 16);
    Wtl[n * 64 + (kh >> 1) + (kk >> 1)] = pk;
  }
}

// ---------------- graph offsets (binary search on sorted batch) + zero gsum
__global__ __launch_bounds__(128) void k_goff(const int* __restrict__ batch,
                                              int* __restrict__ goff,
                                              float* __restrict__ gsum) {
  int t = threadIdx.x;
  if (t < NGRAPH) {
    int lo = 0, hi = NNODES;
    while (lo < hi) {
      int mid = (lo + hi) >> 1;
      if (batch[mid] < t) lo = mid + 1;
      else hi = mid;
    }
    goff[t] = lo;
  }
  if (t == 0) goff[NGRAPH] = NNODES;
  for (int i = t; i < NGRAPH * FDIM; i += 128) gsum[i] = 0.f;
}

// ---------------- MFMA GEMM body (no LDS) ----------------
// H[row,:] = X[row,:] @ W. A-frags from X directly (fp32->bf16), B-frags from
// Wt[n][k] (bf16) directly. Writes packed-bf16 Hb and fused alphas.
__device__ __forceinline__ void gemm_body(int blk, const float* __restrict__ X,
                                          const unsigned* __restrict__ Wt,
                                          const float* __restrict__ a_sL,
                                          const float* __restrict__ a_dL,
                                          unsigned* __restrict__ Hb,
                                          float* __restrict__ as_,
                                          float* __restrict__ ad_) {
  int t = threadIdx.x;
  int lane = t & 63;
  int w = t >> 6;
  int row0 = blk * 64;
  int n16 = lane & 15;
  int quad = lane >> 4;
  int m0 = w * 16;

  int gr = row0 + m0 + n16;
  const float* xp = X + (size_t)min(gr, NNODES - 1) * 128;

  f32x4 acc[8];
#pragma unroll
  for (int nt = 0; nt < 8; ++nt) {
    f32x4 z = {0.f, 0.f, 0.f, 0.f};
    acc[nt] = z;
  }
#pragma unroll
  for (int kk = 0; kk < 4; ++kk) {
    float4 va = *(const float4*)(xp + kk * 32 + quad * 8);
    float4 vb = *(const float4*)(xp + kk * 32 + quad * 8 + 4);
    bf16x8 af;
    af[0] = (short)f2bf(va.x); af[1] = (short)f2bf(va.y);
    af[2] = (short)f2bf(va.z); af[3] = (short)f2bf(va.w);
    af[4] = (short)f2bf(vb.x); af[5] = (short)f2bf(vb.y);
    af[6] = (short)f2bf(vb.z); af[7] = (short)f2bf(vb.w);
#pragma unroll
    for (int nt = 0; nt < 8; ++nt) {
      bf16x8 bf = *(const bf16x8*)(Wt + (size_t)(nt * 16 + n16) * 64 +
                                   kk * 16 + quad * 4);
      acc[nt] =
          __builtin_amdgcn_mfma_f32_16x16x32_bf16(af, bf, acc[nt], 0, 0, 0);
    }
  }

  // epilogue: alpha dots + packed-bf16 H write
  float asv[8], adv[8];
#pragma unroll
  for (int nt = 0; nt < 8; ++nt) {
    asv[nt] = a_sL[nt * 16 + n16];
    adv[nt] = a_dL[nt * 16 + n16];
  }
#pragma unroll
  for (int r = 0; r < 4; ++r) {
    int row = row0 + m0 + quad * 4 + r;
    bool ok = (row < NNODES);
    float ps0 = 0.f, pd0 = 0.f, ps1 = 0.f, pd1 = 0.f;
#pragma unroll
    for (int nt = 0; nt < 4; ++nt) {
      ps0 += acc[nt][r] * asv[nt];
      pd0 += acc[nt][r] * adv[nt];
      ps1 += acc[nt + 4][r] * asv[nt + 4];
      pd1 += acc[nt + 4][r] * adv[nt + 4];
    }
#pragma unroll
    for (int off = 1; off < 16; off <<= 1) {
      ps0 += __shfl_xor(ps0, off, 64);
      pd0 += __shfl_xor(pd0, off, 64);
      ps1 += __shfl_xor(ps1, off, 64);
      pd1 += __shfl_xor(pd1, off, 64);
    }
    if (ok && n16 == 0) {
      as_[row * 2 + 0] = ps0;
      as_[row * 2 + 1] = ps1;
      ad_[row * 2 + 0] = pd0;
      ad_[row * 2 + 1] = pd1;
    }
    if (ok) {
#pragma unroll
      for (int nt = 0; nt < 4; ++nt) {
        unsigned pk = (unsigned)f2bf(acc[nt][r]) |
                      ((unsigned)f2bf(acc[nt + 4][r]) << 16);
        Hb[(size_t)row * 64 + nt * 16 + n16] = pk;
      }
    }
  }
}

__global__ __launch_bounds__(256) void k_gemm(const float* __restrict__ X,
                                              const unsigned* __restrict__ Wt,
                                              const float* __restrict__ a_sL,
                                              const float* __restrict__ a_dL,
                                              unsigned* __restrict__ Hb,
                                              float* __restrict__ as_,
                                              float* __restrict__ ad_) {
  gemm_body(blockIdx.x, X, Wt, a_sL, a_dL, Hb, as_, ad_);
}

// fused: layer-0 GEMM | radix pass A (bucket histogram).
__global__ __launch_bounds__(256) void k_front(
    const float* __restrict__ X, const unsigned* __restrict__ Wt,
    const float* __restrict__ a_sL, const float* __restrict__ a_dL,
    unsigned* __restrict__ Hb, float* __restrict__ as_,
    float* __restrict__ ad_, const int* __restrict__ ei,
    int* __restrict__ bh) {
  int b = blockIdx.x;
  if (b < GEMMB) {
    gemm_body(b, X, Wt, a_sL, a_dL, Hb, as_, ad_);
  } else {
    __shared__ int hist[NB];
    int blk = b - GEMMB;
    int t = threadIdx.x;
    for (int i = t; i < NB; i += 256) hist[i] = 0;
    __syncthreads();
    int e0 = blk * 2048;
#pragma unroll
    for (int i = 0; i < 8; ++i) {
      int e = e0 + i * 256 + t;
      if (e < NEDGES) atomicAdd(&hist[ei[NEDGES + e] >> 7], 1);
    }
    __syncthreads();
    for (int i = t; i < NB; i += 256) bh[i * RADB + blk] = hist[i];
  }
}

// ---------------- scan of bh (col-major [bucket][block]) ----------------
__global__ __launch_bounds__(256) void k_s1(int* __restrict__ sc,
                                            int* __restrict__ bpart) {
  __shared__ int ps[256];
  int t = threadIdx.x;
  int f0 = blockIdx.x * 512 + 2 * t;
  int x0 = (f0 < SCN) ? sc[f0] : 0;
  int x1 = (f0 + 1 < SCN) ? sc[f0 + 1] : 0;
  int pair = x0 + x1;
  ps[t] = pair;
  __syncthreads();
  for (int off = 1; off < 256; off <<= 1) {
    int v = (t >= off) ? ps[t - off] : 0;
    __syncthreads();
    ps[t] += v;
    __syncthreads();
  }
  int ex = ps[t] - pair;
  if (f0 < SCN) sc[f0] = ex;
  if (f0 + 1 < SCN) sc[f0 + 1] = ex + x0;
  if (t == 255) bpart[blockIdx.x] = ps[255];
}

__global__ __launch_bounds__(256) void k_s2(int* __restrict__ bpart) {
  __shared__ int ps[256];
  int t = threadIdx.x;
  int x0 = (2 * t < NS1) ? bpart[2 * t] : 0;
  int x1 = (2 * t + 1 < NS1) ? bpart[2 * t + 1] : 0;
  int pair = x0 + x1;
  ps[t] = pair;
  __syncthreads();
  for (int off = 1; off < 256; off <<= 1) {
    int v = (t >= off) ? ps[t - off] : 0;
    __syncthreads();
    ps[t] += v;
    __syncthreads();
  }
  int ex = ps[t] - pair;
  if (2 * t < NS1) bpart[2 * t] = ex;
  if (2 * t + 1 < NS1) bpart[2 * t + 1] = ex + x0;
}

__global__ __launch_bounds__(256) void k_s3(int* __restrict__ sc,
                                            const int* __restrict__ bpart) {
  int t = threadIdx.x;
  int f0 = blockIdx.x * 512 + 2 * t;
  int add = bpart[blockIdx.x];
  if (f0 < SCN) sc[f0] += add;
  if (f0 + 1 < SCN) sc[f0 + 1] += add;
}

// ---------------- radix pass B: scatter edges into bucket regions ---------
__global__ __launch_bounds__(256) void k_passB(const int* __restrict__ ei,
                                               const int* __restrict__ sc,
                                               unsigned* __restrict__ ebuf) {
  __shared__ int curs[NB];
  int blk = blockIdx.x, t = threadIdx.x;
  for (int i = t; i < NB; i += 256) curs[i] = sc[i * RADB + blk];
  __syncthreads();
  int e0 = blk * 2048;
#pragma unroll
  for (int i = 0; i < 8; ++i) {
    int e = e0 + i * 256 + t;
    if (e < NEDGES) {
      int s = ei[e];
      int d = ei[NEDGES + e];
      int pos = atomicAdd(&curs[d >> 7], 1);
      ebuf[pos] = ((unsigned)s << 7) | (unsigned)(d & 127);
    }
  }
}

// ---------------- radix pass C: per-bucket CSR finalize ----------------
__global__ __launch_bounds__(256) void k_passC(const unsigned* __restrict__ ebuf,
                                               const int* __restrict__ sc,
                                               int* __restrict__ row_ptr,
                                               int* __restrict__ csr) {
  __shared__ int deg[128];
  __shared__ int scn[128];
  int b = blockIdx.x, t = threadIdx.x;
  int node0 = b * 128;
  int nn = min(128, NNODES - node0);
  int estart = sc[b * RADB];
  int eend = (b + 1 < NB) ? sc[(b + 1) * RADB] : NEDGES;
  if (t < 128) deg[t] = 0;
  __syncthreads();
  for (int e = estart + t; e < eend; e += 256)
    atomicAdd(&deg[ebuf[e] & 127], 1);
  __syncthreads();
  if (t < 128) scn[t] = (t < nn) ? deg[t] + 1 : 0;
  __syncthreads();
  for (int off = 1; off < 128; off <<= 1) {
    int v = (t < 128 && t >= off) ? scn[t - off] : 0;
    __syncthreads();
    if (t < 128) scn[t] += v;
    __syncthreads();
  }
  int base = estart + node0;
  if (t < nn) {
    int st = base + (t ? scn[t - 1] : 0);
    row_ptr[node0 + t] = st;
    csr[st] = node0 + t;  // self-loop at rank 0
    deg[t] = st + 1;      // reuse as cursor
  }
  if (b == 0 && t == 0) row_ptr[NNODES] = NEDGES + NNODES;
  __syncthreads();
  for (int e = estart + t; e < eend; e += 256) {
    unsigned v = ebuf[e];
    int pos = atomicAdd(&deg[v & 127], 1);
    csr[pos] = (int)(v >> 7);
  }
}

// One wave per node: softmax (shift-invariant) + aggregation (both heads).
__global__ __launch_bounds__(256) void k_aggregate(
    const unsigned* __restrict__ Hb, const float* __restrict__ as_,
    const float* __restrict__ ad_, const int* __restrict__ row_ptr,
    const int* __restrict__ csr, const float* __restrict__ bias,
    float* __restrict__ Xout) {
  __shared__ float2 wb[4][64];
  __shared__ int sb[4][64];
  int wv = threadIdx.x >> 6;
  int lane = threadIdx.x & 63;
  int node = blockIdx.x * 4 + wv;
  if (node >= NNODES) return;
  int rs = row_ptr[node], re = row_ptr[node + 1];
  float2 adv = *(const float2*)&ad_[node * 2];
  const unsigned* Hl = Hb + lane;

  float z0 = 0.f, z1 = 0.f, acc0 = 0.f, acc1 = 0.f;
  for (int base = rs; base < re; base += 64) {
    int j = base + lane;
    float p0 = 0.f, p1 = 0.f;
    int s = 0;
    if (j < re) {
      s = csr[j];
      float2 asv = *(const float2*)&as_[s * 2];
      float e0 = asv.x + adv.x; e0 = (e0 > 0.f) ? e0 : NEG_SLOPE * e0;
      float e1 = asv.y + adv.y; e1 = (e1 > 0.f) ? e1 : NEG_SLOPE * e1;
      p0 = __expf(e0);
      p1 = __expf(e1);
    }
    z0 += p0;
    z1 += p1;
    wb[wv][lane] = make_float2(p0, p1);
    sb[wv][lane] = s;
    WAVE_SYNC();
    int cl = min(64, re - base);
    int jj = 0;
    for (; jj + 8 <= cl; jj += 8) {
      unsigned v0 = Hl[(size_t)sb[wv][jj + 0] * 64];
      unsigned v1 = Hl[(size_t)sb[wv][jj + 1] * 64];
      unsigned v2 = Hl[(size_t)sb[wv][jj + 2] * 64];
      unsigned v3 = Hl[(size_t)sb[wv][jj + 3] * 64];
      unsigned v4 = Hl[(size_t)sb[wv][jj + 4] * 64];
      unsigned v5 = Hl[(size_t)sb[wv][jj + 5] * 64];
      unsigned v6 = Hl[(size_t)sb[wv][jj + 6] * 64];
      unsigned v7 = Hl[(size_t)sb[wv][jj + 7] * 64];
      float2 w0 = wb[wv][jj + 0], w1 = wb[wv][jj + 1];
      float2 w2 = wb[wv][jj + 2], w3 = wb[wv][jj + 3];
      float2 w4 = wb[wv][jj + 4], w5 = wb[wv][jj + 5];
      float2 w6 = wb[wv][jj + 6], w7 = wb[wv][jj + 7];
      acc0 += w0.x * bflo(v0); acc1 += w0.y * bfhi(v0);
      acc0 += w1.x * bflo(v1); acc1 += w1.y * bfhi(v1);
      acc0 += w2.x * bflo(v2); acc1 += w2.y * bfhi(v2);
      acc0 += w3.x * bflo(v3); acc1 += w3.y * bfhi(v3);
      acc0 += w4.x * bflo(v4); acc1 += w4.y * bfhi(v4);
      acc0 += w5.x * bflo(v5); acc1 += w5.y * bfhi(v5);
      acc0 += w6.x * bflo(v6); acc1 += w6.y * bfhi(v6);
      acc0 += w7.x * bflo(v7); acc1 += w7.y * bfhi(v7);
    }
    for (; jj < cl; ++jj) {
      unsigned v = Hl[(size_t)sb[wv][jj] * 64];
      float2 w = wb[wv][jj];
      acc0 += w.x * bflo(v);
      acc1 += w.y * bfhi(v);
    }
    WAVE_SYNC();
  }
#pragma unroll
  for (int off = 32; off > 0; off >>= 1) {
    z0 += __shfl_xor(z0, off, 64);
    z1 += __shfl_xor(z1, off, 64);
  }
  float o0 = acc0 / z0 + bias[lane];
  float o1 = acc1 / z1 + bias[64 + lane];
  o0 = (o0 > 0.f) ? o0 : expm1f(o0);  // ELU
  o1 = (o1 > 0.f) ? o1 : expm1f(o1);
  Xout[(size_t)node * 128 + lane] = o0;
  Xout[(size_t)node * 128 + 64 + lane] = o1;
}

// ---------------- pooling: 8 chunks/graph, coalesced contiguous rows ------
__global__ __launch_bounds__(256) void k_pool2(const float* __restrict__ Xf,
                                               const int* __restrict__ goff,
                                               float* __restrict__ gsum) {
  __shared__ float red[128];
  int b = blockIdx.x;
  int g = b >> 3, ch = b & 7;
  int t = threadIdx.x;
  int c = t & 127, rh = t >> 7;
  int s = goff[g], e = goff[g + 1];
  int len = e - s;
  int c0 = s + (len * ch) / PCH;
  int c1 = s + (len * (ch + 1)) / PCH;
  float acc = 0.f;
  for (int n = c0 + rh; n < c1; n += 2) acc += Xf[(size_t)n * 128 + c];
  if (rh) red[c] = acc;
  __syncthreads();
  if (!rh) atomicAdd(&gsum[g * FDIM + c], acc + red[c]);
}

// ---------------- classifier ----------------
__global__ __launch_bounds__(64) void k_final(const float* __restrict__ gsum,
                                              const int* __restrict__ goff,
                                              const float* __restrict__ lw,
                                              const float* __restrict__ lb,
                                              float* __restrict__ out) {
  int g = threadIdx.x;
  float cnt = (float)(goff[g + 1] - goff[g]);
  float inv = 1.f / fmaxf(cnt, 1.f);
  float lg[NCLS];
#pragma unroll
  for (int k = 0; k < NCLS; ++k) lg[k] = lb[k];
  for (int c = 0; c < FDIM; ++c) {
    float pv = gsum[g * FDIM + c] * inv;
#pragma unroll
    for (int k = 0; k < NCLS; ++k) lg[k] += pv * lw[c * NCLS + k];
  }
  float mx = lg[0];
#pragma unroll
  for (int k = 1; k < NCLS; ++k) mx = fmaxf(mx, lg[k]);
  float s = 0.f;
#pragma unroll
  for (int k = 0; k < NCLS; ++k) {
    lg[k] = expf(lg[k] - mx);
    s += lg[k];
  }
  float invs = 1.f / s;
#pragma unroll
  for (int k = 0; k < NCLS; ++k) out[g * NCLS + k] = lg[k] * invs;
}

// ---------------- launch ----------------

extern "C" void kernel_launch(void* const* d_in, const int* in_sizes, int n_in,
                              void* d_out, int out_size, void* d_ws,
                              size_t ws_size, hipStream_t stream) {
  const float* x = (const float*)d_in[0];
  const int* ei = (const int*)d_in[1];
  const int* batch = (const int*)d_in[2];
  const float* W = (const float*)d_in[3];
  const float* a_s = (const float*)d_in[4];
  const float* a_d = (const float*)d_in[5];
  const float* bias = (const float*)d_in[6];
  const float* lw = (const float*)d_in[7];
  const float* lb = (const float*)d_in[8];
  float* out = (float*)d_out;

  unsigned* Hb = (unsigned*)d_ws;                  // N*64 packed bf16 pairs
  float* xb = (float*)(Hb + (size_t)NNODES * 64);  // N*128
  float* as_ = xb + (size_t)NNODES * 128;          // N*2
  float* ad_ = as_ + (size_t)NNODES * 2;           // N*2
  float* gsum = ad_ + (size_t)NNODES * 2;          // 64*128
  int* goff = (int*)(gsum + NGRAPH * FDIM);        // 65
  int* row_ptr = goff + (NGRAPH + 1);              // N+1
  int* csr = row_ptr + (NNODES + 1);               // E+N
  int* sc = csr + (NEDGES + NNODES);               // NB*RADB
  int* bpart = sc + SCN;                           // NS1
  unsigned* ebuf = (unsigned*)(bpart + NS1);       // E (+pad)
  unsigned* Wt = ebuf + (NEDGES + 1024);           // 3*8192 (bf16 W^T)

  k_wprep<<<NLAYERS, 256, 0, stream>>>(W, Wt);
  k_goff<<<1, 128, 0, stream>>>(batch, goff, gsum);
  // layer-0 GEMM overlapped with radix pass A
  k_front<<<GEMMB + RADB, 256, 0, stream>>>(x, Wt, a_s, a_d, Hb, as_, ad_, ei,
                                            sc);
  k_s1<<<NS1, 256, 0, stream>>>(sc, bpart);
  k_s2<<<1, 256, 0, stream>>>(bpart);
  k_s3<<<NS1, 256, 0, stream>>>(sc, bpart);
  k_passB<<<RADB, 256, 0, stream>>>(ei, sc, ebuf);
  k_passC<<<NB, 256, 0, stream>>>(ebuf, sc, row_ptr, csr);

  for (int l = 0; l < NLAYERS; ++l) {
    if (l > 0) {
      k_gemm<<<GEMMB, 256, 0, stream>>>(xb, Wt + (size_t)l * FDIM * FDIM / 2,
                                        a_s + l * FDIM, a_d + l * FDIM, Hb,
                                        as_, ad_);
    }
    k_aggregate<<<(NNODES + 3) / 4, 256, 0, stream>>>(
        Hb, as_, ad_, row_ptr, csr, bias + l * FDIM, xb);
  }
  k_pool2<<<NGRAPH * PCH, 256, 0, stream>>>(xb, goff, gsum);
  k_final<<<1, 64, 0, stream>>>(gsum, goff, lw, lb, out);
}